// Round 2
// baseline (91.259 us; speedup 1.0000x reference)
//
#include <hip/hip_runtime.h>
#include <math.h>

#define B_  16
#define T_  16
#define N_  256
#define D_  384
#define Q_  384
#define K_  16
#define BT_ (B_ * T_)

// ---------------------------------------------------------------------------
// Kernel 1: q_proj[bt] = queries[bt] @ W_in + b_in
// 32 blocks x 384 threads; each block handles 8 bt rows (amortizes W_in).
// ---------------------------------------------------------------------------
__global__ __launch_bounds__(384)
void qproj_kernel(const float* __restrict__ queries,  // [BT_, Q_]
                  const float* __restrict__ W_in,     // [Q_, D_]
                  const float* __restrict__ b_in,     // [D_]
                  float* __restrict__ qp)             // [BT_, D_]
{
    const int bt0 = blockIdx.x * 8;
    const int tid = threadIdx.x;          // 0..383 == output d

    __shared__ float s_q[8][Q_];
    #pragma unroll
    for (int r = 0; r < 8; ++r)
        s_q[r][tid] = queries[(size_t)(bt0 + r) * Q_ + tid];
    __syncthreads();

    float acc[8];
    const float bi = b_in[tid];
    #pragma unroll
    for (int r = 0; r < 8; ++r) acc[r] = bi;

    #pragma unroll 4
    for (int q = 0; q < Q_; ++q) {
        const float w = W_in[(size_t)q * D_ + tid];
        #pragma unroll
        for (int r = 0; r < 8; ++r) acc[r] += s_q[r][q] * w;
    }
    #pragma unroll
    for (int r = 0; r < 8; ++r)
        qp[(size_t)(bt0 + r) * D_ + tid] = acc[r];
}

// ---------------------------------------------------------------------------
// Kernel 2: scores[bt, n] = dot(qp[bt], patch[bt, n, :])
// grid (16 row-tiles, BT_) x 256 threads; each block does 16 rows.
// 16-lane groups per row, float4 loads, shuffle reduce.
// ---------------------------------------------------------------------------
__global__ __launch_bounds__(256)
void scores_kernel(const float* __restrict__ patch,   // [BT_, N_, D_]
                   const float* __restrict__ qp,      // [BT_, D_]
                   float* __restrict__ sc)            // [BT_, N_]
{
    const int bt   = blockIdx.y;
    const int tile = blockIdx.x;          // 0..15
    const int tid  = threadIdx.x;         // 0..255
    const int lane = tid & 63;
    const int wave = tid >> 6;            // 0..3
    const int g    = lane >> 4;           // 0..3 row in wave
    const int sl   = lane & 15;

    __shared__ float s_qp[D_];
    s_qp[tid] = qp[(size_t)bt * D_ + tid];
    if (tid < D_ - 256) s_qp[tid + 256] = qp[(size_t)bt * D_ + tid + 256];
    __syncthreads();

    const int n = tile * 16 + wave * 4 + g;
    const float* prow = patch + ((size_t)bt * N_ + n) * D_;
    const float4* s_qp4 = reinterpret_cast<const float4*>(s_qp);

    float p = 0.f;
    #pragma unroll
    for (int c = 0; c < 6; ++c) {
        const float4 a = *reinterpret_cast<const float4*>(prow + c * 64 + 4 * sl);
        const float4 b = s_qp4[c * 16 + sl];
        p += a.x * b.x + a.y * b.y + a.z * b.z + a.w * b.w;
    }
    #pragma unroll
    for (int off = 8; off; off >>= 1)
        p += __shfl_xor(p, off, 16);
    if (sl == 0) sc[(size_t)bt * N_ + n] = p;   // TEMP == 1
}

// ---------------------------------------------------------------------------
// Kernel 3: softmax + exact top-K + weighted sum + output projection
// 256 blocks x 384 threads.
// ---------------------------------------------------------------------------
__global__ __launch_bounds__(384)
void finish_kernel(const float* __restrict__ patch,   // [BT_, N_, D_]
                   const float* __restrict__ sc,      // [BT_, N_]
                   const float* __restrict__ W_out,   // [D_, Q_]
                   const float* __restrict__ b_out,   // [Q_]
                   float* __restrict__ out)           // [BT_, Q_]
{
    const int bt   = blockIdx.x;
    const int tid  = threadIdx.x;         // 0..383
    const int lane = tid & 63;
    const int wave = tid >> 6;            // 0..5

    __shared__ float s_sc[N_];
    __shared__ float s_red[6];
    __shared__ float s_red2[6][2];
    __shared__ float s_w[K_];
    __shared__ int   s_ix[K_];
    __shared__ float s_od[D_];

    const float* __restrict__ ptile = patch + (size_t)bt * N_ * D_;

    if (tid < N_) s_sc[tid] = sc[(size_t)bt * N_ + tid];
    __syncthreads();

    // block max over N_
    {
        float v = (tid < N_) ? s_sc[tid] : -INFINITY;
        #pragma unroll
        for (int off = 32; off; off >>= 1) v = fmaxf(v, __shfl_xor(v, off));
        if (lane == 0) s_red[wave] = v;
    }
    __syncthreads();
    float mx = s_red[0];
    #pragma unroll
    for (int i = 1; i < 6; ++i) mx = fmaxf(mx, s_red[i]);

    // rank by comparison count: permutation of 0..N_-1, jax tie-break
    float e = 0.f;
    int   cnt = N_;
    if (tid < N_) {
        const float si = s_sc[tid];
        cnt = 0;
        for (int j = 0; j < N_; ++j) {
            const float sj = s_sc[j];
            cnt += (int)(sj > si) | ((int)(sj == si) & (int)(j < tid));
        }
        e = __expf(si - mx);
    }

    // Z = sum exp, SK = sum of top-K exp
    {
        float z  = e;
        float sk = (cnt < K_) ? e : 0.f;
        #pragma unroll
        for (int off = 32; off; off >>= 1) {
            z  += __shfl_xor(z, off);
            sk += __shfl_xor(sk, off);
        }
        if (lane == 0) { s_red2[wave][0] = z; s_red2[wave][1] = sk; }
    }
    __syncthreads();
    float Z = 0.f, SK = 0.f;
    #pragma unroll
    for (int i = 0; i < 6; ++i) { Z += s_red2[i][0]; SK += s_red2[i][1]; }

    // weight_i = e_i / (SK + EPS*Z)
    const float inv = 1.f / (SK + 1e-8f * Z);
    if (tid < N_ && cnt < K_) {
        s_ix[cnt] = tid;
        s_w[cnt]  = e * inv;
    }
    __syncthreads();

    // weighted sum over K selected rows (L2/L3-hot)
    {
        float acc = 0.f;
        #pragma unroll
        for (int j = 0; j < K_; ++j)
            acc += s_w[j] * ptile[(size_t)s_ix[j] * D_ + tid];
        s_od[tid] = acc;
    }
    __syncthreads();

    // output projection
    {
        float acc = b_out[tid];
        #pragma unroll 4
        for (int d = 0; d < D_; ++d)
            acc += s_od[d] * W_out[(size_t)d * Q_ + tid];
        out[(size_t)bt * Q_ + tid] = acc;
    }
}

extern "C" void kernel_launch(void* const* d_in, const int* in_sizes, int n_in,
                              void* d_out, int out_size, void* d_ws, size_t ws_size,
                              hipStream_t stream) {
    const float* queries = (const float*)d_in[0];
    const float* patch   = (const float*)d_in[1];
    const float* W_in    = (const float*)d_in[2];
    const float* b_in    = (const float*)d_in[3];
    const float* W_out   = (const float*)d_in[4];
    const float* b_out   = (const float*)d_in[5];
    float* out = (float*)d_out;

    float* qp = (float*)d_ws;                 // [BT_, D_]
    float* sc = qp + (size_t)BT_ * D_;        // [BT_, N_]

    qproj_kernel<<<dim3(BT_ / 8), dim3(384), 0, stream>>>(queries, W_in, b_in, qp);
    scores_kernel<<<dim3(16, BT_), dim3(256), 0, stream>>>(patch, qp, sc);
    finish_kernel<<<dim3(BT_), dim3(384), 0, stream>>>(patch, sc, W_out, b_out, out);
}

// Round 3
// 44.406 us; speedup vs baseline: 2.0551x; 2.0551x over previous
//
#include <hip/hip_runtime.h>
#include <math.h>

#define B_  16
#define T_  16
#define N_  256
#define D_  384
#define Q_  384
#define K_  16
#define BT_ (B_ * T_)
#define NT  1024   // 16 waves per block

// Fully fused: one 1024-thread block per (b,t). No d_ws (workspace poison-fill
// of the whole ws buffer lands in the timed graph — R2 lesson).
//
//  1. q_proj = queries[bt] @ W_in + b_in       (2-way split-K GEMV, 768 thr)
//  2. scores[n] = dot(q_proj, patch[bt,n,:])   (16 waves x 4 rows x 4 iters)
//  3. softmax + exact top-K via rank count (jax tie-break by index)
//  4. out_d = sum_j w_j * patch[bt,idx_j,:]    (2-way split over j)
//  5. out = out_d @ W_out + b_out              (2-way split-K GEMV, 768 thr)
__global__ __launch_bounds__(NT)
void attn_topk_kernel(const float* __restrict__ queries,   // [BT_, Q_]
                      const float* __restrict__ patch,     // [BT_, N_, D_]
                      const float* __restrict__ W_in,      // [Q_, D_]
                      const float* __restrict__ b_in,      // [D_]
                      const float* __restrict__ W_out,     // [D_, Q_]
                      const float* __restrict__ b_out,     // [Q_]
                      float* __restrict__ out)             // [BT_, Q_]
{
    const int bt   = blockIdx.x;
    const int tid  = threadIdx.x;       // 0..1023
    const int lane = tid & 63;
    const int wave = tid >> 6;          // 0..15

    __shared__ float s_q[Q_];
    __shared__ float s_part[2 * D_];    // split-K partials (reused 3x)
    __shared__ float s_qp[D_];
    __shared__ float s_sc[N_];
    __shared__ float s_red[4];
    __shared__ float s_red2[4][2];
    __shared__ float s_w[K_];
    __shared__ int   s_ix[K_];
    __shared__ float s_od[D_];

    const float* __restrict__ ptile = patch + (size_t)bt * N_ * D_;

    if (tid < Q_) s_q[tid] = queries[(size_t)bt * Q_ + tid];
    __syncthreads();

    // ---- 1. q_proj: thread (half, d) sums q in [half*192, half*192+192) ----
    if (tid < 2 * D_) {
        const int half = tid >= D_;
        const int d    = tid - half * D_;
        const int q0   = half * (Q_ / 2);
        float acc = 0.f;
        #pragma unroll 8
        for (int q = q0; q < q0 + Q_ / 2; ++q)
            acc += s_q[q] * W_in[(size_t)q * D_ + d];
        s_part[tid] = acc;
    }
    __syncthreads();
    if (tid < D_) s_qp[tid] = s_part[tid] + s_part[tid + D_] + b_in[tid];
    __syncthreads();

    // ---- 2. scores: 16 waves x 4 rows per iter, 4 iters ----
    {
        const int g  = lane >> 4;       // 0..3
        const int sl = lane & 15;
        const float4* s_qp4 = reinterpret_cast<const float4*>(s_qp);
        #pragma unroll
        for (int it = 0; it < N_ / 64; ++it) {
            const int n = it * 64 + wave * 4 + g;
            const float* prow = ptile + (size_t)n * D_;
            float p = 0.f;
            #pragma unroll
            for (int c = 0; c < 6; ++c) {
                const float4 a = *reinterpret_cast<const float4*>(prow + c * 64 + 4 * sl);
                const float4 b = s_qp4[c * 16 + sl];
                p += a.x * b.x + a.y * b.y + a.z * b.z + a.w * b.w;
            }
            #pragma unroll
            for (int off = 8; off; off >>= 1)
                p += __shfl_xor(p, off, 16);
            if (sl == 0) s_sc[n] = p;   // TEMP == 1
        }
    }
    __syncthreads();

    // ---- 3. softmax + top-K ----
    if (tid < N_) {
        float v = s_sc[tid];
        #pragma unroll
        for (int off = 32; off; off >>= 1) v = fmaxf(v, __shfl_xor(v, off));
        if (lane == 0) s_red[wave] = v;
    }
    __syncthreads();
    const float mx = fmaxf(fmaxf(s_red[0], s_red[1]), fmaxf(s_red[2], s_red[3]));

    float e = 0.f;
    int   cnt = N_;
    if (tid < N_) {
        const float si = s_sc[tid];
        cnt = 0;
        #pragma unroll 8
        for (int j = 0; j < N_; ++j) {
            const float sj = s_sc[j];
            cnt += (int)(sj > si) | ((int)(sj == si) & (int)(j < tid));
        }
        e = __expf(si - mx);

        float z  = e;
        float sk = (cnt < K_) ? e : 0.f;
        #pragma unroll
        for (int off = 32; off; off >>= 1) {
            z  += __shfl_xor(z, off);
            sk += __shfl_xor(sk, off);
        }
        if (lane == 0) { s_red2[wave][0] = z; s_red2[wave][1] = sk; }
    }
    __syncthreads();
    float Z = 0.f, SK = 0.f;
    #pragma unroll
    for (int i = 0; i < 4; ++i) { Z += s_red2[i][0]; SK += s_red2[i][1]; }

    // weight_i = softmax_i / (sum_topk + EPS) = e_i / (SK + EPS*Z)
    const float inv = 1.f / (SK + 1e-8f * Z);
    if (tid < N_ && cnt < K_) {
        s_ix[cnt] = tid;
        s_w[cnt]  = e * inv;
    }
    __syncthreads();

    // ---- 4. weighted sum over K rows: thread (half, d) sums 8 rows ----
    if (tid < 2 * D_) {
        const int half = tid >= D_;
        const int d    = tid - half * D_;
        const int j0   = half * (K_ / 2);
        float acc = 0.f;
        #pragma unroll
        for (int j = j0; j < j0 + K_ / 2; ++j)
            acc += s_w[j] * ptile[(size_t)s_ix[j] * D_ + d];
        s_part[tid] = acc;
    }
    __syncthreads();
    if (tid < D_) s_od[tid] = s_part[tid] + s_part[tid + D_];
    __syncthreads();

    // ---- 5. out-proj: thread (half, q) sums d in [half*192, +192) ----
    if (tid < 2 * Q_) {
        const int half = tid >= Q_;
        const int q    = tid - half * Q_;
        const int d0   = half * (D_ / 2);
        float acc = 0.f;
        #pragma unroll 8
        for (int d = d0; d < d0 + D_ / 2; ++d)
            acc += s_od[d] * W_out[(size_t)d * Q_ + q];
        s_part[tid] = acc;
    }
    __syncthreads();
    if (tid < Q_)
        out[(size_t)bt * Q_ + tid] = s_part[tid] + s_part[tid + Q_] + b_out[tid];
}

extern "C" void kernel_launch(void* const* d_in, const int* in_sizes, int n_in,
                              void* d_out, int out_size, void* d_ws, size_t ws_size,
                              hipStream_t stream) {
    const float* queries = (const float*)d_in[0];
    const float* patch   = (const float*)d_in[1];
    const float* W_in    = (const float*)d_in[2];
    const float* b_in    = (const float*)d_in[3];
    const float* W_out   = (const float*)d_in[4];
    const float* b_out   = (const float*)d_in[5];
    float* out = (float*)d_out;

    attn_topk_kernel<<<dim3(BT_), dim3(NT), 0, stream>>>(
        queries, patch, W_in, b_in, W_out, b_out, out);
}